// Round 10
// baseline (404.940 us; speedup 1.0000x reference)
//
#include <hip/hip_runtime.h>

#define NUM_K   4096
#define CDIM    64
#define HWDIM   4096            // 64*64
#define NVEC    65536           // 16 * 64 * 64
#define CHW     (CDIM * HWDIM)  // 262144
#define KT      32              // codes per k-tile
#define NKT_SL  64              // k-tiles per slice (2048 codes)
#define NPAIR   (NKT_SL / 2)    // 32 barrier groups (2 tiles per barrier)
#define TAUH    6e-3f           // rescue margin (validated r8)
#define SBIAS   128.0f          // score bias: s' = 128 + (wsq - 2 x.w)/2 > 0 always
#define XSTR    66              // xs stride in bf16 (33 dwords, odd -> conflict-free)

// ---- output layout (floats, reference return order) ----
#define O_Q     0               // quantized_ste [16,64,64,64] = 4194304
#define O_LOSS  4194304
#define O_IDX   4194305         // [16,64,64] = 65536
#define O_W     4259841         // new_weight [4096,64]
#define O_CS    4521985         // new_cluster_size [4096]
#define O_EW    4526081         // new_ema_w [4096,64]
// O_Q region triple-duty: wh/wl bf16 codebook (prep->argmin), then xsorted
// fp32 [65536][64] (xscatter->dwsum), then the real Q output (qgather).

// ---- workspace layout (floats) ----  high-water 409600 floats = 1.64 MB
#define W_WSQ    0               // wsq/2 + SBIAS [4096]
#define W_CNT    4096            // int counts [4096], zeroed by prep
#define W_LOSS   8192
#define W_ESUM   8193
#define W_PRE    8704            // int prefix [4096]
#define W_KEY    16384           // u64 keys [2][65536] = 262144 floats
#define W_DW     16384           // dw [262144] overlays keys (dead after combine)
#define W_B2     278528          // float b2 [2][65536] = 131072 floats
#define W_IDX    278528          // int idx_arr[65536] overlays b2s slice 0 (after combine)
#define W_RANK   344064          // int rank[65536] overlays b2s slice 1 (after combine)

typedef unsigned long long u64;
typedef __bf16 bf16x8 __attribute__((ext_vector_type(8)));
typedef __bf16 bf16x2 __attribute__((ext_vector_type(2)));
typedef float  f32x4  __attribute__((ext_vector_type(4)));

__device__ __forceinline__ unsigned f2ord(float f) {
    unsigned u = __float_as_uint(f);
    return (u & 0x80000000u) ? ~u : (u | 0x80000000u);
}
__device__ __forceinline__ unsigned umn(unsigned a, unsigned b) { return a < b ? a : b; }
__device__ __forceinline__ unsigned umx(unsigned a, unsigned b) { return a > b ? a : b; }

// wsq/2 + SBIAS, bf16 hi/lo codebook, zero counts/loss, esum (block 0).
__global__ void __launch_bounds__(256)
prep_kernel(const float* __restrict__ w, float* __restrict__ wsqh,
            __bf16* __restrict__ wh, __bf16* __restrict__ wl,
            int* __restrict__ cnt, float* __restrict__ loss_a,
            const float* __restrict__ ecs, float* __restrict__ esum) {
    __shared__ float red[256];
    int gid = blockIdx.x * 256 + threadIdx.x;
    if (gid < 4096) cnt[gid] = 0;
    if (gid == 4096) loss_a[0] = 0.f;

    int wv = threadIdx.x >> 6, lane = threadIdx.x & 63;
    int row = blockIdx.x * 4 + wv;
    float v = w[row * CDIM + lane];
    __bf16 h = (__bf16)v;
    __bf16 l = (__bf16)(v - (float)h);         // v - hi exact in fp32
    wh[row * CDIM + lane] = h;
    wl[row * CDIM + lane] = l;
    float sq = v * v;
#pragma unroll
    for (int m = 1; m < 64; m <<= 1) sq += __shfl_xor(sq, m, 64);
    if (lane == 0) wsqh[row] = 0.5f * sq + SBIAS;

    if (blockIdx.x == 0) {
        float s = 0.f;
        for (int k = threadIdx.x; k < NUM_K; k += 256) s += ecs[k];
        red[threadIdx.x] = s;
        __syncthreads();
        for (int st = 128; st > 0; st >>= 1) {
            if (threadIdx.x < st) red[threadIdx.x] += red[threadIdx.x + st];
            __syncthreads();
        }
        if (threadIdx.x == 0) esum[0] = red[0];
    }
}

// Fused bf16x3-split MFMA GEMM + argmin (unchanged from r9: K-split x2,
// packed u32 top-2 keys, kt-pair dbuf, LDS overlay, 4 blocks/CU).
__global__ void __launch_bounds__(256, 4)
argmin_mfma(const float* __restrict__ x,
            const __bf16* __restrict__ wh_g, const __bf16* __restrict__ wl_g,
            const float* __restrict__ wsqh_g,
            u64* __restrict__ keys, float* __restrict__ b2s) {
    extern __shared__ __bf16 smem[];           // 33792 B
    __bf16* xs_h = smem;
    __bf16* xs_l = smem + 128 * XSTR;
    __bf16* bs   = smem;                       // overlay after xs is dead

    int t = threadIdx.x, wv = t >> 6, lane = t & 63;
    int n0 = blockIdx.x * 128;
    int b = n0 >> 12, hw0 = n0 & (HWDIM - 1);
    int kbase = blockIdx.y * (NUM_K / 2);
    int slice = blockIdx.y;

#pragma unroll
    for (int half = 0; half < 2; ++half) {
        int i = half * 64 + lane;
        const float* xb = x + b * CHW + hw0 + i;
#pragma unroll
        for (int j = 0; j < 8; ++j) {
            int c0 = wv * 16 + j * 2;
            float v0 = -xb[c0 * HWDIM];
            float v1 = -xb[(c0 + 1) * HWDIM];
            __bf16 h0 = (__bf16)v0, h1 = (__bf16)v1;
            bf16x2 hh = {h0, h1};
            bf16x2 ll = {(__bf16)(v0 - (float)h0), (__bf16)(v1 - (float)h1)};
            *(bf16x2*)(xs_h + i * XSTR + c0) = hh;
            *(bf16x2*)(xs_l + i * XSTR + c0) = ll;
        }
    }
    __syncthreads();

    int nn = lane & 15, q4 = lane >> 4;
    bf16x8 ah[2][2], al[2][2];
#pragma unroll
    for (int m = 0; m < 2; ++m) {
        int id = wv * 32 + m * 16 + nn;
#pragma unroll
        for (int ch = 0; ch < 2; ++ch) {
            union { unsigned u[4]; bf16x8 v; } th, tl;
            const unsigned* ph = (const unsigned*)(xs_h + id * XSTR + (q4 + ch * 4) * 8);
            const unsigned* pl = (const unsigned*)(xs_l + id * XSTR + (q4 + ch * 4) * 8);
#pragma unroll
            for (int jj = 0; jj < 4; ++jj) { th.u[jj] = ph[jj]; tl.u[jj] = pl[jj]; }
            ah[m][ch] = th.v; al[m][ch] = tl.v;
        }
    }
    __syncthreads();

    int sr = t & 15, sj = (t >> 4) & 7, ss = (t >> 7) & 1;
    long goff = (long)(ss * 16 + sr) * 64 + sj * 8;

#pragma unroll
    for (int tau = 0; tau < 2; ++tau) {
        long g = (long)(kbase + tau * KT) * 64 + goff;
        *(bf16x8*)(bs + tau * 4096 + t * 8)        = *(const bf16x8*)(wh_g + g);
        *(bf16x8*)(bs + tau * 4096 + 2048 + t * 8) = *(const bf16x8*)(wl_g + g);
    }
    __syncthreads();

    unsigned b1k[8], b2k[8];
#pragma unroll
    for (int s = 0; s < 8; ++s) { b1k[s] = 0xFFFFFFFFu; b2k[s] = 0xFFFFFFFFu; }

    for (int kp = 0; kp < NPAIR; ++kp) {
        bf16x8 sth[2], stl[2];
        bool pre = (kp + 1 < NPAIR);
        if (pre) {
#pragma unroll
            for (int tau = 0; tau < 2; ++tau) {
                long g = (long)(kbase + ((kp + 1) * 2 + tau) * KT) * 64 + goff;
                sth[tau] = *(const bf16x8*)(wh_g + g);
                stl[tau] = *(const bf16x8*)(wl_g + g);
            }
        }
#pragma unroll
        for (int tau = 0; tau < 2; ++tau) {
            int kt = kp * 2 + tau;
            const __bf16* base = bs + (kp & 1) * 8192 + tau * 4096;
            int k0 = kbase + kt * KT;
            float wA = wsqh_g[k0 + nn];
            float wB = wsqh_g[k0 + 16 + nn];
            unsigned tA = (unsigned)(kt * 2), tB = (unsigned)(kt * 2 + 1);

            int o1 = (q4 * 16 + nn) * 8, o2 = ((q4 + 4) * 16 + nn) * 8;
            bf16x8 bh0A = *(const bf16x8*)(base + o1);
            bf16x8 bh1A = *(const bf16x8*)(base + o2);
            bf16x8 bh0B = *(const bf16x8*)(base + 1024 + o1);
            bf16x8 bh1B = *(const bf16x8*)(base + 1024 + o2);
            bf16x8 bl0A = *(const bf16x8*)(base + 2048 + o1);
            bf16x8 bl1A = *(const bf16x8*)(base + 2048 + o2);
            bf16x8 bl0B = *(const bf16x8*)(base + 3072 + o1);
            bf16x8 bl1B = *(const bf16x8*)(base + 3072 + o2);

#pragma unroll
            for (int m = 0; m < 2; ++m) {
                f32x4 accA = {wA, wA, wA, wA};
                f32x4 accB = {wB, wB, wB, wB};
                accA = __builtin_amdgcn_mfma_f32_16x16x32_bf16(ah[m][0], bh0A, accA, 0, 0, 0);
                accA = __builtin_amdgcn_mfma_f32_16x16x32_bf16(ah[m][1], bh1A, accA, 0, 0, 0);
                accA = __builtin_amdgcn_mfma_f32_16x16x32_bf16(al[m][0], bh0A, accA, 0, 0, 0);
                accA = __builtin_amdgcn_mfma_f32_16x16x32_bf16(al[m][1], bh1A, accA, 0, 0, 0);
                accA = __builtin_amdgcn_mfma_f32_16x16x32_bf16(ah[m][0], bl0A, accA, 0, 0, 0);
                accA = __builtin_amdgcn_mfma_f32_16x16x32_bf16(ah[m][1], bl1A, accA, 0, 0, 0);
                accB = __builtin_amdgcn_mfma_f32_16x16x32_bf16(ah[m][0], bh0B, accB, 0, 0, 0);
                accB = __builtin_amdgcn_mfma_f32_16x16x32_bf16(ah[m][1], bh1B, accB, 0, 0, 0);
                accB = __builtin_amdgcn_mfma_f32_16x16x32_bf16(al[m][0], bh0B, accB, 0, 0, 0);
                accB = __builtin_amdgcn_mfma_f32_16x16x32_bf16(al[m][1], bh1B, accB, 0, 0, 0);
                accB = __builtin_amdgcn_mfma_f32_16x16x32_bf16(ah[m][0], bl0B, accB, 0, 0, 0);
                accB = __builtin_amdgcn_mfma_f32_16x16x32_bf16(ah[m][1], bl1B, accB, 0, 0, 0);
#pragma unroll
                for (int r = 0; r < 4; ++r) {
                    unsigned ka = (__float_as_uint(accA[r]) & 0xFFFFFF80u) | tA;
                    unsigned kb = (__float_as_uint(accB[r]) & 0xFFFFFF80u) | tB;
                    unsigned lo = umn(ka, kb), hi = umx(ka, kb);
                    int s8 = m * 4 + r;
                    b2k[s8] = umn(umn(b2k[s8], umx(b1k[s8], lo)), hi);
                    b1k[s8] = umn(b1k[s8], lo);
                }
            }
        }
        if (pre) {
            __bf16* nb = bs + ((kp + 1) & 1) * 8192;
#pragma unroll
            for (int tau = 0; tau < 2; ++tau) {
                *(bf16x8*)(nb + tau * 4096 + t * 8)        = sth[tau];
                *(bf16x8*)(nb + tau * 4096 + 2048 + t * 8) = stl[tau];
            }
        }
        __syncthreads();
    }

    float s1[8], sb2[8]; int code[8];
#pragma unroll
    for (int s = 0; s < 8; ++s) {
        s1[s]  = __uint_as_float(b1k[s] & 0xFFFFFF80u);
        sb2[s] = __uint_as_float(b2k[s] & 0xFFFFFF80u);
        code[s] = (kbase + nn) + (int)(b1k[s] & 0x7Fu) * 16;
    }
#pragma unroll
    for (int msk = 1; msk < 16; msk <<= 1) {
#pragma unroll
        for (int s = 0; s < 8; ++s) {
            float os1 = __shfl_xor(s1[s], msk, 64);
            float ob2 = __shfl_xor(sb2[s], msk, 64);
            int   oc  = __shfl_xor(code[s], msk, 64);
            sb2[s] = fminf(fminf(sb2[s], ob2), fmaxf(s1[s], os1));
            if (os1 < s1[s]) code[s] = oc;
            s1[s] = fminf(s1[s], os1);
        }
    }
    if (nn == 0) {
#pragma unroll
        for (int s = 0; s < 8; ++s) {
            int m = s >> 2, r = s & 3;
            int v = n0 + wv * 32 + m * 16 + q4 * 4 + r;
            keys[slice * NVEC + v] = ((u64)__float_as_uint(s1[s]) << 32) | (unsigned)code[s];
            b2s[slice * NVEC + v]  = sb2[s];
        }
    }
}

// Slice-combine + block-local exact rescue + histogram/rank + O_IDX.
// 256 blocks x 256 threads, one vector per thread. idx_arr/rank overlay b2s
// (each thread reads its b2s slots before writing the same slots).
__global__ void __launch_bounds__(256)
combine_kernel(const float* __restrict__ x, const float* __restrict__ w,
               const float* __restrict__ wsqh,
               const u64* __restrict__ keys, const float* __restrict__ b2s,
               int* __restrict__ cnt, int* __restrict__ idx_arr,
               int* __restrict__ rank, float* __restrict__ out) {
    __shared__ unsigned fmask[8];
    __shared__ int fix[256];
    __shared__ float xv[CDIM];
    __shared__ u64 rk[256];

    int t = threadIdx.x;
    int n = blockIdx.x * 256 + t;
    if (t < 8) fmask[t] = 0;
    __syncthreads();

    u64 ka = keys[n], kb = keys[NVEC + n];
    u64 km = ka < kb ? ka : kb;            // equal packed score -> lower code wins
    int idx = (int)(km & 0xFFFFFFFFu);
    float a1 = __uint_as_float((unsigned)(ka >> 32));
    float c1 = __uint_as_float((unsigned)(kb >> 32));
    float lo = fminf(a1, c1), hi = fmaxf(a1, c1);
    float m2 = fminf(fminf(b2s[n], b2s[NVEC + n]), hi);
    bool fl = (m2 - lo < TAUH);
    if (fl) atomicOr(&fmask[t >> 5], 1u << (t & 31));
    __syncthreads();

    // block-local exact fp32 rescue (rare; ~1-3 per block)
    for (int h = 0; h < 8; ++h) {
        unsigned m = fmask[h];
        while (m) {
            int v = __ffs(m) - 1; m &= m - 1;
            int vv = h * 32 + v;
            int nn2 = blockIdx.x * 256 + vv;
            int bb = nn2 >> 12, hw = nn2 & (HWDIM - 1);
            if (t < CDIM) xv[t] = x[bb * CHW + t * HWDIM + hw];
            __syncthreads();
            u64 local = ~0ull;
            for (int k = t; k < NUM_K; k += 256) {
                const float* wr = w + k * CDIM;
                float d0 = 0.f, d1 = 0.f, d2 = 0.f, d3 = 0.f;
#pragma unroll
                for (int c = 0; c < CDIM; c += 4) {
                    d0 = fmaf(xv[c + 0], wr[c + 0], d0);
                    d1 = fmaf(xv[c + 1], wr[c + 1], d1);
                    d2 = fmaf(xv[c + 2], wr[c + 2], d2);
                    d3 = fmaf(xv[c + 3], wr[c + 3], d3);
                }
                float s = wsqh[k] - ((d0 + d1) + (d2 + d3));   // biased, exact
                u64 key = ((u64)f2ord(s) << 32) | (unsigned)k; // lower k wins ties
                local = local < key ? local : key;
            }
            rk[t] = local;
            __syncthreads();
            for (int st = 128; st > 0; st >>= 1) {
                if (t < st) rk[t] = rk[t] < rk[t + st] ? rk[t] : rk[t + st];
                __syncthreads();
            }
            if (t == 0) fix[vv] = (int)(rk[0] & 0xFFFFFFFFu);
            __syncthreads();
        }
    }
    if (fl) idx = fix[t];

    idx_arr[n] = idx;
    rank[n] = atomicAdd(&cnt[idx], 1);     // exact int histogram + sort rank
    out[O_IDX + n] = (float)idx;
}

// Exclusive prefix sum over the 4096 counts (single block).
__global__ void __launch_bounds__(256)
prefix_kernel(const int* __restrict__ cnt, int* __restrict__ prefix) {
    __shared__ int ls[256];
    int t = threadIdx.x;
    int loc[16], s = 0;
#pragma unroll
    for (int j = 0; j < 16; ++j) { loc[j] = cnt[t * 16 + j]; s += loc[j]; }
    ls[t] = s;
    __syncthreads();
    for (int off = 1; off < 256; off <<= 1) {
        int v = (t >= off) ? ls[t - off] : 0;
        __syncthreads();
        ls[t] += v;
        __syncthreads();
    }
    int run = ls[t] - s;                   // exclusive prefix of this group
#pragma unroll
    for (int j = 0; j < 16; ++j) { prefix[t * 16 + j] = run; run += loc[j]; }
}

// Scatter x rows into code-sorted order (xsorted in the O_Q region).
// Stage 64 vectors via coalesced reads -> LDS -> 256B coalesced row writes.
__global__ void __launch_bounds__(256)
xscatter_kernel(const float* __restrict__ x, const int* __restrict__ idx_arr,
                const int* __restrict__ rank, const int* __restrict__ prefix,
                float* __restrict__ xsorted) {
    __shared__ float xs[64][CDIM + 1];
    __shared__ int slot[64];
    int t = threadIdx.x;
    int n0 = blockIdx.x * 64;
    int b = n0 >> 12, hw0 = n0 & (HWDIM - 1);
    if (t < 64) slot[t] = prefix[idx_arr[n0 + t]] + rank[n0 + t];

    int lane = t & 63, wv = t >> 6;
    const float* xbase = x + b * CHW + hw0;
#pragma unroll
    for (int j = 0; j < 16; ++j) {
        int c = wv + j * 4;
        xs[lane][c] = xbase[c * HWDIM + lane];
    }
    __syncthreads();
#pragma unroll
    for (int i = 0; i < 16; ++i) {
        int nl = wv * 16 + i;
        xsorted[(size_t)slot[nl] * CDIM + lane] = xs[nl][lane];
    }
}

// Segment sums: one wave per code, contiguous coalesced reads, NO atomics.
__global__ void __launch_bounds__(256)
dwsum_kernel(const float* __restrict__ xsorted, const int* __restrict__ cnt,
             const int* __restrict__ prefix, float* __restrict__ dw) {
    int t = threadIdx.x, wv = t >> 6, lane = t & 63;
    int k = blockIdx.x * 4 + wv;           // 1024 blocks x 4 waves = 4096 codes
    int start = prefix[k], len = cnt[k];
    const float* p = xsorted + (size_t)start * CDIM + lane;
    float a0 = 0.f, a1 = 0.f, a2 = 0.f, a3 = 0.f;
    int i = 0;
    for (; i + 4 <= len; i += 4) {
        a0 += p[(size_t)(i    ) * CDIM];
        a1 += p[(size_t)(i + 1) * CDIM];
        a2 += p[(size_t)(i + 2) * CDIM];
        a3 += p[(size_t)(i + 3) * CDIM];
    }
    for (; i < len; ++i) a0 += p[(size_t)i * CDIM];
    dw[k * CDIM + lane] = (a0 + a1) + (a2 + a3);
}

// Gather Q = w[idx] (16 prefetched loads/thread for MLP), STE write, loss.
// Overwrites the xsorted scratch with the real quantized_ste output.
__global__ void __launch_bounds__(256)
qgather_kernel(const float* __restrict__ x, const float* __restrict__ w,
               const int* __restrict__ idx_arr, float* __restrict__ out,
               float* __restrict__ loss_acc) {
    __shared__ int sidx[64];
    __shared__ float red[256];
    int t = threadIdx.x;
    int n0 = blockIdx.x * 64;
    int b = n0 >> 12, hw0 = n0 & (HWDIM - 1);
    if (t < 64) sidx[t] = idx_arr[n0 + t];
    __syncthreads();

    int lane = t & 63, wv = t >> 6;
    const float* wrow = w + (size_t)sidx[lane] * CDIM;
    float qv[16];
#pragma unroll
    for (int j = 0; j < 16; ++j) qv[j] = wrow[wv + j * 4];   // 16 outstanding gathers

    const float* xbase = x + b * CHW + hw0;
    float* qbase = out + O_Q + b * CHW + hw0;
    float lsum = 0.f;
#pragma unroll
    for (int j = 0; j < 16; ++j) {
        int c = wv + j * 4;
        float xvv = xbase[c * HWDIM + lane];
        float d = qv[j] - xvv;
        qbase[c * HWDIM + lane] = xvv + d;     // STE arithmetic as reference
        lsum = fmaf(d, d, lsum);
    }
    red[t] = lsum;
    __syncthreads();
    for (int st = 128; st > 0; st >>= 1) {
        if (t < st) red[t] += red[t + st];
        __syncthreads();
    }
    if (t == 0) atomicAdd(loss_acc, red[0]);
}

// Fused elementwise finalize: new_cluster_size, new_ema_w, new_weight, loss.
__global__ void __launch_bounds__(256)
finalize_all(const float* __restrict__ ecs, const int* __restrict__ cnt,
             const float* __restrict__ ema_w, const float* __restrict__ dw,
             const float* __restrict__ loss_acc, const float* __restrict__ esum,
             float* __restrict__ out) {
    int e = blockIdx.x * 256 + threadIdx.x;   // 0..262143
    int k = e >> 6;                            // wave-uniform
    float ncs = 0.99f * ecs[k] + 0.01f * (float)cnt[k];
    if ((e & 63) == 0) out[O_CS + k] = ncs;
    if (e == 0) out[O_LOSS] = 0.25f * loss_acc[0] / 4194304.0f;
    float n = 0.99f * esum[0] + 0.01f * 65536.0f;   // sum(counts) == NVEC exactly
    float cs = (ncs + 1e-5f) / (n + NUM_K * 1e-5f) * n;
    float ew = 0.99f * ema_w[e] + 0.01f * dw[e];
    out[O_EW + e] = ew;
    out[O_W + e] = ew / cs;
}

extern "C" void kernel_launch(void* const* d_in, const int* in_sizes, int n_in,
                              void* d_out, int out_size, void* d_ws, size_t ws_size,
                              hipStream_t stream) {
    const float* x     = (const float*)d_in[0];
    const float* w     = (const float*)d_in[1];
    const float* ecs   = (const float*)d_in[2];
    const float* ema_w = (const float*)d_in[3];
    float* out = (float*)d_out;
    float* ws  = (float*)d_ws;

    float* wsqh   = ws + W_WSQ;
    int*   cnt    = (int*)(ws + W_CNT);
    float* loss_a = ws + W_LOSS;
    float* esum   = ws + W_ESUM;
    int*   prefix = (int*)(ws + W_PRE);
    u64*   keys   = (u64*)(ws + W_KEY);
    float* b2s    = ws + W_B2;
    int*   idx_a  = (int*)(ws + W_IDX);    // overlays b2s slice 0 (after combine)
    int*   rank   = (int*)(ws + W_RANK);   // overlays b2s slice 1 (after combine)
    float* dw     = ws + W_DW;             // overlays keys (after combine)

    // O_Q region scratch: wh/wl bf16 codebook, then xsorted fp32 [65536][64]
    __bf16* wh = (__bf16*)out;
    __bf16* wl = wh + NUM_K * CDIM;
    float* xsorted = out + O_Q;

    prep_kernel<<<NUM_K / 4, 256, 0, stream>>>(w, wsqh, wh, wl, cnt, loss_a, ecs, esum);
    argmin_mfma<<<dim3(NVEC / 128, 2), 256, 33792, stream>>>(x, wh, wl, wsqh, keys, b2s);
    combine_kernel<<<NVEC / 256, 256, 0, stream>>>(x, w, wsqh, keys, b2s, cnt, idx_a, rank, out);
    prefix_kernel<<<1, 256, 0, stream>>>(cnt, prefix);
    xscatter_kernel<<<NVEC / 64, 256, 0, stream>>>(x, idx_a, rank, prefix, xsorted);
    dwsum_kernel<<<NUM_K / 4, 256, 0, stream>>>(xsorted, cnt, prefix, dw);
    qgather_kernel<<<NVEC / 64, 256, 0, stream>>>(x, w, idx_a, out, loss_a);
    finalize_all<<<CHW / 256, 256, 0, stream>>>(ecs, cnt, ema_w, dw, loss_a, esum, out);
}

// Round 11
// 376.154 us; speedup vs baseline: 1.0765x; 1.0765x over previous
//
#include <hip/hip_runtime.h>

#define NUM_K   4096
#define CDIM    64
#define HWDIM   4096            // 64*64
#define NVEC    65536           // 16 * 64 * 64
#define CHW     (CDIM * HWDIM)  // 262144
#define KT      32              // codes per k-tile
#define NKT_SL  64              // k-tiles per slice (2048 codes)
#define NPAIR   (NKT_SL / 2)    // 32 barrier groups (2 tiles per barrier)
#define TAUH    6e-3f           // rescue margin (validated r8)
#define SBIAS   128.0f          // score bias: s' = 128 + (wsq - 2 x.w)/2 > 0 always
#define XSTR    66              // xs stride in bf16 (33 dwords, odd -> conflict-free)

// ---- output layout (floats, reference return order) ----
#define O_Q     0               // quantized_ste [16,64,64,64] = 4194304
#define O_LOSS  4194304
#define O_IDX   4194305         // [16,64,64] = 65536
#define O_W     4259841         // new_weight [4096,64]
#define O_CS    4521985         // new_cluster_size [4096]
#define O_EW    4526081         // new_ema_w [4096,64]
// O_Q region dual-duty: wh/wl bf16 codebook (prep->argmin/—dead after),
// then the real quantized output (qgather).

// ---- workspace layout (floats) ----  high-water 475136 floats = 1.9 MB
#define W_WSQ    0               // wsq/2 + SBIAS [4096]
#define W_CNT    4096            // int counts [4096], zeroed by prep
#define W_LOSS   8192
#define W_ESUM   8193
#define W_RCNT   8194            // int rescue count
#define W_PRE    8704            // int prefix [4096]
#define W_KEY    16384           // u64 keys [2][65536] = 262144 floats
#define W_NSORT  16384           // int nsorted[65536] overlays keys (dead after combine)
#define W_B2     278528          // float b2 [2][65536]
#define W_IDX    278528          // int idx_arr[65536] overlays b2s slice 0 (same-thread RAW)
#define W_RANK   344064          // int rank[65536] overlays b2s slice 1 (same-thread RAW)
#define W_RLIST  409600          // int rlist[65536]

typedef unsigned long long u64;
typedef __bf16 bf16x8 __attribute__((ext_vector_type(8)));
typedef __bf16 bf16x2 __attribute__((ext_vector_type(2)));
typedef float  f32x4  __attribute__((ext_vector_type(4)));

__device__ __forceinline__ unsigned f2ord(float f) {
    unsigned u = __float_as_uint(f);
    return (u & 0x80000000u) ? ~u : (u | 0x80000000u);
}
__device__ __forceinline__ unsigned umn(unsigned a, unsigned b) { return a < b ? a : b; }
__device__ __forceinline__ unsigned umx(unsigned a, unsigned b) { return a > b ? a : b; }

// wsq/2 + SBIAS, bf16 hi/lo codebook, zero cnt/loss/rcnt, esum (block 0).
__global__ void __launch_bounds__(256)
prep_kernel(const float* __restrict__ w, float* __restrict__ wsqh,
            __bf16* __restrict__ wh, __bf16* __restrict__ wl,
            int* __restrict__ cnt, float* __restrict__ loss_a,
            int* __restrict__ rcnt, const float* __restrict__ ecs,
            float* __restrict__ esum) {
    __shared__ float red[256];
    int gid = blockIdx.x * 256 + threadIdx.x;
    if (gid < 4096) cnt[gid] = 0;
    if (gid == 4096) loss_a[0] = 0.f;
    if (gid == 4097) rcnt[0] = 0;

    int wv = threadIdx.x >> 6, lane = threadIdx.x & 63;
    int row = blockIdx.x * 4 + wv;
    float v = w[row * CDIM + lane];
    __bf16 h = (__bf16)v;
    __bf16 l = (__bf16)(v - (float)h);         // v - hi exact in fp32
    wh[row * CDIM + lane] = h;
    wl[row * CDIM + lane] = l;
    float sq = v * v;
#pragma unroll
    for (int m = 1; m < 64; m <<= 1) sq += __shfl_xor(sq, m, 64);
    if (lane == 0) wsqh[row] = 0.5f * sq + SBIAS;

    if (blockIdx.x == 0) {
        float s = 0.f;
        for (int k = threadIdx.x; k < NUM_K; k += 256) s += ecs[k];
        red[threadIdx.x] = s;
        __syncthreads();
        for (int st = 128; st > 0; st >>= 1) {
            if (threadIdx.x < st) red[threadIdx.x] += red[threadIdx.x + st];
            __syncthreads();
        }
        if (threadIdx.x == 0) esum[0] = red[0];
    }
}

// Fused bf16x3-split MFMA GEMM + argmin (unchanged from r9/r10).
__global__ void __launch_bounds__(256, 4)
argmin_mfma(const float* __restrict__ x,
            const __bf16* __restrict__ wh_g, const __bf16* __restrict__ wl_g,
            const float* __restrict__ wsqh_g,
            u64* __restrict__ keys, float* __restrict__ b2s) {
    extern __shared__ __bf16 smem[];           // 33792 B
    __bf16* xs_h = smem;
    __bf16* xs_l = smem + 128 * XSTR;
    __bf16* bs   = smem;                       // overlay after xs is dead

    int t = threadIdx.x, wv = t >> 6, lane = t & 63;
    int n0 = blockIdx.x * 128;
    int b = n0 >> 12, hw0 = n0 & (HWDIM - 1);
    int kbase = blockIdx.y * (NUM_K / 2);
    int slice = blockIdx.y;

#pragma unroll
    for (int half = 0; half < 2; ++half) {
        int i = half * 64 + lane;
        const float* xb = x + b * CHW + hw0 + i;
#pragma unroll
        for (int j = 0; j < 8; ++j) {
            int c0 = wv * 16 + j * 2;
            float v0 = -xb[c0 * HWDIM];
            float v1 = -xb[(c0 + 1) * HWDIM];
            __bf16 h0 = (__bf16)v0, h1 = (__bf16)v1;
            bf16x2 hh = {h0, h1};
            bf16x2 ll = {(__bf16)(v0 - (float)h0), (__bf16)(v1 - (float)h1)};
            *(bf16x2*)(xs_h + i * XSTR + c0) = hh;
            *(bf16x2*)(xs_l + i * XSTR + c0) = ll;
        }
    }
    __syncthreads();

    int nn = lane & 15, q4 = lane >> 4;
    bf16x8 ah[2][2], al[2][2];
#pragma unroll
    for (int m = 0; m < 2; ++m) {
        int id = wv * 32 + m * 16 + nn;
#pragma unroll
        for (int ch = 0; ch < 2; ++ch) {
            union { unsigned u[4]; bf16x8 v; } th, tl;
            const unsigned* ph = (const unsigned*)(xs_h + id * XSTR + (q4 + ch * 4) * 8);
            const unsigned* pl = (const unsigned*)(xs_l + id * XSTR + (q4 + ch * 4) * 8);
#pragma unroll
            for (int jj = 0; jj < 4; ++jj) { th.u[jj] = ph[jj]; tl.u[jj] = pl[jj]; }
            ah[m][ch] = th.v; al[m][ch] = tl.v;
        }
    }
    __syncthreads();

    int sr = t & 15, sj = (t >> 4) & 7, ss = (t >> 7) & 1;
    long goff = (long)(ss * 16 + sr) * 64 + sj * 8;

#pragma unroll
    for (int tau = 0; tau < 2; ++tau) {
        long g = (long)(kbase + tau * KT) * 64 + goff;
        *(bf16x8*)(bs + tau * 4096 + t * 8)        = *(const bf16x8*)(wh_g + g);
        *(bf16x8*)(bs + tau * 4096 + 2048 + t * 8) = *(const bf16x8*)(wl_g + g);
    }
    __syncthreads();

    unsigned b1k[8], b2k[8];
#pragma unroll
    for (int s = 0; s < 8; ++s) { b1k[s] = 0xFFFFFFFFu; b2k[s] = 0xFFFFFFFFu; }

    for (int kp = 0; kp < NPAIR; ++kp) {
        bf16x8 sth[2], stl[2];
        bool pre = (kp + 1 < NPAIR);
        if (pre) {
#pragma unroll
            for (int tau = 0; tau < 2; ++tau) {
                long g = (long)(kbase + ((kp + 1) * 2 + tau) * KT) * 64 + goff;
                sth[tau] = *(const bf16x8*)(wh_g + g);
                stl[tau] = *(const bf16x8*)(wl_g + g);
            }
        }
#pragma unroll
        for (int tau = 0; tau < 2; ++tau) {
            int kt = kp * 2 + tau;
            const __bf16* base = bs + (kp & 1) * 8192 + tau * 4096;
            int k0 = kbase + kt * KT;
            float wA = wsqh_g[k0 + nn];
            float wB = wsqh_g[k0 + 16 + nn];
            unsigned tA = (unsigned)(kt * 2), tB = (unsigned)(kt * 2 + 1);

            int o1 = (q4 * 16 + nn) * 8, o2 = ((q4 + 4) * 16 + nn) * 8;
            bf16x8 bh0A = *(const bf16x8*)(base + o1);
            bf16x8 bh1A = *(const bf16x8*)(base + o2);
            bf16x8 bh0B = *(const bf16x8*)(base + 1024 + o1);
            bf16x8 bh1B = *(const bf16x8*)(base + 1024 + o2);
            bf16x8 bl0A = *(const bf16x8*)(base + 2048 + o1);
            bf16x8 bl1A = *(const bf16x8*)(base + 2048 + o2);
            bf16x8 bl0B = *(const bf16x8*)(base + 3072 + o1);
            bf16x8 bl1B = *(const bf16x8*)(base + 3072 + o2);

#pragma unroll
            for (int m = 0; m < 2; ++m) {
                f32x4 accA = {wA, wA, wA, wA};
                f32x4 accB = {wB, wB, wB, wB};
                accA = __builtin_amdgcn_mfma_f32_16x16x32_bf16(ah[m][0], bh0A, accA, 0, 0, 0);
                accA = __builtin_amdgcn_mfma_f32_16x16x32_bf16(ah[m][1], bh1A, accA, 0, 0, 0);
                accA = __builtin_amdgcn_mfma_f32_16x16x32_bf16(al[m][0], bh0A, accA, 0, 0, 0);
                accA = __builtin_amdgcn_mfma_f32_16x16x32_bf16(al[m][1], bh1A, accA, 0, 0, 0);
                accA = __builtin_amdgcn_mfma_f32_16x16x32_bf16(ah[m][0], bl0A, accA, 0, 0, 0);
                accA = __builtin_amdgcn_mfma_f32_16x16x32_bf16(ah[m][1], bl1A, accA, 0, 0, 0);
                accB = __builtin_amdgcn_mfma_f32_16x16x32_bf16(ah[m][0], bh0B, accB, 0, 0, 0);
                accB = __builtin_amdgcn_mfma_f32_16x16x32_bf16(ah[m][1], bh1B, accB, 0, 0, 0);
                accB = __builtin_amdgcn_mfma_f32_16x16x32_bf16(al[m][0], bh0B, accB, 0, 0, 0);
                accB = __builtin_amdgcn_mfma_f32_16x16x32_bf16(al[m][1], bh1B, accB, 0, 0, 0);
                accB = __builtin_amdgcn_mfma_f32_16x16x32_bf16(ah[m][0], bl0B, accB, 0, 0, 0);
                accB = __builtin_amdgcn_mfma_f32_16x16x32_bf16(ah[m][1], bl1B, accB, 0, 0, 0);
#pragma unroll
                for (int r = 0; r < 4; ++r) {
                    unsigned ka = (__float_as_uint(accA[r]) & 0xFFFFFF80u) | tA;
                    unsigned kb = (__float_as_uint(accB[r]) & 0xFFFFFF80u) | tB;
                    unsigned lo = umn(ka, kb), hi = umx(ka, kb);
                    int s8 = m * 4 + r;
                    b2k[s8] = umn(umn(b2k[s8], umx(b1k[s8], lo)), hi);
                    b1k[s8] = umn(b1k[s8], lo);
                }
            }
        }
        if (pre) {
            __bf16* nb = bs + ((kp + 1) & 1) * 8192;
#pragma unroll
            for (int tau = 0; tau < 2; ++tau) {
                *(bf16x8*)(nb + tau * 4096 + t * 8)        = sth[tau];
                *(bf16x8*)(nb + tau * 4096 + 2048 + t * 8) = stl[tau];
            }
        }
        __syncthreads();
    }

    float s1[8], sb2[8]; int code[8];
#pragma unroll
    for (int s = 0; s < 8; ++s) {
        s1[s]  = __uint_as_float(b1k[s] & 0xFFFFFF80u);
        sb2[s] = __uint_as_float(b2k[s] & 0xFFFFFF80u);
        code[s] = (kbase + nn) + (int)(b1k[s] & 0x7Fu) * 16;
    }
#pragma unroll
    for (int msk = 1; msk < 16; msk <<= 1) {
#pragma unroll
        for (int s = 0; s < 8; ++s) {
            float os1 = __shfl_xor(s1[s], msk, 64);
            float ob2 = __shfl_xor(sb2[s], msk, 64);
            int   oc  = __shfl_xor(code[s], msk, 64);
            sb2[s] = fminf(fminf(sb2[s], ob2), fmaxf(s1[s], os1));
            if (os1 < s1[s]) code[s] = oc;
            s1[s] = fminf(s1[s], os1);
        }
    }
    if (nn == 0) {
#pragma unroll
        for (int s = 0; s < 8; ++s) {
            int m = s >> 2, r = s & 3;
            int v = n0 + wv * 32 + m * 16 + q4 * 4 + r;
            keys[slice * NVEC + v] = ((u64)__float_as_uint(s1[s]) << 32) | (unsigned)code[s];
            b2s[slice * NVEC + v]  = sb2[s];
        }
    }
}

// Pure per-thread slice-combine: idx; non-flagged -> rank/cnt/O_IDX now,
// flagged -> append to rlist (rescue claims its rank later; rank slots only
// need uniqueness within a code, sum order is irrelevant).
__global__ void __launch_bounds__(256)
combine_kernel(const u64* __restrict__ keys, const float* __restrict__ b2s,
               int* __restrict__ cnt, int* __restrict__ idx_arr,
               int* __restrict__ rank, int* __restrict__ rcnt,
               int* __restrict__ rlist, float* __restrict__ out) {
    int n = blockIdx.x * 256 + threadIdx.x;
    u64 ka = keys[n], kb = keys[NVEC + n];
    u64 km = ka < kb ? ka : kb;            // equal packed score -> lower code wins
    int idx = (int)(km & 0xFFFFFFFFu);
    float a1 = __uint_as_float((unsigned)(ka >> 32));
    float c1 = __uint_as_float((unsigned)(kb >> 32));
    float lo = fminf(a1, c1), hi = fmaxf(a1, c1);
    float m2 = fminf(fminf(b2s[n], b2s[NVEC + n]), hi);
    if (m2 - lo < TAUH) {
        int p = atomicAdd(rcnt, 1);
        rlist[p] = n;                      // ambiguous: exact rescan decides
    } else {
        idx_arr[n] = idx;
        rank[n] = atomicAdd(&cnt[idx], 1);
        out[O_IDX + n] = (float)idx;
    }
}

// Distributed exact fp32 rescue: 256 blocks block-stride over rlist (balanced,
// no straggler CU — r10's block-local version serialized ~40 scans on one CU).
__global__ void __launch_bounds__(256)
rescue_kernel(const float* __restrict__ x, const float* __restrict__ w,
              const float* __restrict__ wsqh, int* __restrict__ idx_arr,
              int* __restrict__ rank, int* __restrict__ cnt,
              const int* __restrict__ rcnt, const int* __restrict__ rlist,
              float* __restrict__ out) {
    __shared__ float xv[CDIM];
    __shared__ u64 rk[256];
    int t = threadIdx.x;
    int total = *rcnt;
    for (int i = blockIdx.x; i < total; i += gridDim.x) {
        int n = rlist[i];
        int b = n >> 12, hw = n & (HWDIM - 1);
        if (t < CDIM) xv[t] = x[b * CHW + t * HWDIM + hw];
        __syncthreads();
        u64 local = ~0ull;
        for (int k = t; k < NUM_K; k += 256) {
            const float* wr = w + k * CDIM;
            float d0 = 0.f, d1 = 0.f, d2 = 0.f, d3 = 0.f;
#pragma unroll
            for (int c = 0; c < CDIM; c += 4) {
                d0 = fmaf(xv[c + 0], wr[c + 0], d0);
                d1 = fmaf(xv[c + 1], wr[c + 1], d1);
                d2 = fmaf(xv[c + 2], wr[c + 2], d2);
                d3 = fmaf(xv[c + 3], wr[c + 3], d3);
            }
            float s = wsqh[k] - ((d0 + d1) + (d2 + d3));   // biased, exact fp32
            u64 key = ((u64)f2ord(s) << 32) | (unsigned)k; // lower k wins ties
            local = local < key ? local : key;
        }
        rk[t] = local;
        __syncthreads();
        for (int st = 128; st > 0; st >>= 1) {
            if (t < st) rk[t] = rk[t] < rk[t + st] ? rk[t] : rk[t + st];
            __syncthreads();
        }
        if (t == 0) {
            int best = (int)(rk[0] & 0xFFFFFFFFu);
            idx_arr[n] = best;
            rank[n] = atomicAdd(&cnt[best], 1);
            out[O_IDX + n] = (float)best;
        }
        __syncthreads();
    }
}

// Exclusive prefix sum over the 4096 counts (single block).
__global__ void __launch_bounds__(256)
prefix_kernel(const int* __restrict__ cnt, int* __restrict__ prefix) {
    __shared__ int ls[256];
    int t = threadIdx.x;
    int loc[16], s = 0;
#pragma unroll
    for (int j = 0; j < 16; ++j) { loc[j] = cnt[t * 16 + j]; s += loc[j]; }
    ls[t] = s;
    __syncthreads();
    for (int off = 1; off < 256; off <<= 1) {
        int v = (t >= off) ? ls[t - off] : 0;
        __syncthreads();
        ls[t] += v;
        __syncthreads();
    }
    int run = ls[t] - s;
#pragma unroll
    for (int j = 0; j < 16; ++j) { prefix[t * 16 + j] = run; run += loc[j]; }
}

// nsorted[prefix[idx]+rank] = n  (code-grouped member lists; 4B scattered writes)
__global__ void __launch_bounds__(256)
nsort_kernel(const int* __restrict__ idx_arr, const int* __restrict__ rank,
             const int* __restrict__ prefix, int* __restrict__ nsorted) {
    int n = blockIdx.x * 256 + threadIdx.x;
    nsorted[prefix[idx_arr[n]] + rank[n]] = n;
}

// Gather Q = w[idx], STE write, loss. Runs BEFORE dwsum (no xsorted anymore,
// so overwriting the O_Q region is safe — wh/wl are dead after argmin).
__global__ void __launch_bounds__(256)
qgather_kernel(const float* __restrict__ x, const float* __restrict__ w,
               const int* __restrict__ idx_arr, float* __restrict__ out,
               float* __restrict__ loss_acc) {
    __shared__ int sidx[64];
    __shared__ float red[256];
    int t = threadIdx.x;
    int n0 = blockIdx.x * 64;
    int b = n0 >> 12, hw0 = n0 & (HWDIM - 1);
    if (t < 64) sidx[t] = idx_arr[n0 + t];
    __syncthreads();

    int lane = t & 63, wv = t >> 6;
    const float* wrow = w + (size_t)sidx[lane] * CDIM;
    float qv[16];
#pragma unroll
    for (int j = 0; j < 16; ++j) qv[j] = wrow[wv + j * 4];   // 16 outstanding gathers

    const float* xbase = x + b * CHW + hw0;
    float* qbase = out + O_Q + b * CHW + hw0;
    float lsum = 0.f;
#pragma unroll
    for (int j = 0; j < 16; ++j) {
        int c = wv + j * 4;
        float xvv = xbase[c * HWDIM + lane];
        float d = qv[j] - xvv;
        qbase[c * HWDIM + lane] = xvv + d;     // STE arithmetic as reference
        lsum = fmaf(d, d, lsum);
    }
    red[t] = lsum;
    __syncthreads();
    for (int st = 128; st > 0; st >>= 1) {
        if (t < st) red[t] += red[t + st];
        __syncthreads();
    }
    if (t == 0) atomicAdd(loss_acc, red[0]);
}

// Segment-sum dw by gathering x via nsorted (L2-served 64B-line gathers,
// zero atomics), FUSED with the elementwise finalize: one wave per code.
__global__ void __launch_bounds__(256)
dwsum_fin_kernel(const float* __restrict__ x, const int* __restrict__ nsorted,
                 const int* __restrict__ cnt, const int* __restrict__ prefix,
                 const float* __restrict__ ecs, const float* __restrict__ ema_w,
                 const float* __restrict__ esum, const float* __restrict__ loss_acc,
                 float* __restrict__ out) {
    int t = threadIdx.x, wv = t >> 6, lane = t & 63;
    int k = blockIdx.x * 4 + wv;           // 1024 blocks x 4 waves = 4096 codes
    int start = prefix[k], len = cnt[k];
    const int* ns = nsorted + start;
    float a0 = 0.f, a1 = 0.f, a2 = 0.f, a3 = 0.f;
    int i = 0;
    for (; i + 4 <= len; i += 4) {         // 4-way MLP on L2 gathers
        int n0 = ns[i], n1 = ns[i + 1], n2 = ns[i + 2], n3 = ns[i + 3];
        a0 += x[(n0 >> 12) * CHW + lane * HWDIM + (n0 & (HWDIM - 1))];
        a1 += x[(n1 >> 12) * CHW + lane * HWDIM + (n1 & (HWDIM - 1))];
        a2 += x[(n2 >> 12) * CHW + lane * HWDIM + (n2 & (HWDIM - 1))];
        a3 += x[(n3 >> 12) * CHW + lane * HWDIM + (n3 & (HWDIM - 1))];
    }
    for (; i < len; ++i) {
        int n = ns[i];
        a0 += x[(n >> 12) * CHW + lane * HWDIM + (n & (HWDIM - 1))];
    }
    float dwv = (a0 + a1) + (a2 + a3);

    float ncs = 0.99f * ecs[k] + 0.01f * (float)len;
    float nn = 0.99f * esum[0] + 0.01f * 65536.0f;   // sum(cnt) == NVEC exactly
    float cs = (ncs + 1e-5f) / (nn + NUM_K * 1e-5f) * nn;
    int e = k * CDIM + lane;
    float ew = 0.99f * ema_w[e] + 0.01f * dwv;
    out[O_EW + e] = ew;
    out[O_W + e] = ew / cs;
    if (lane == 0) out[O_CS + k] = ncs;
    if (k == 0 && lane == 0) out[O_LOSS] = 0.25f * loss_acc[0] / 4194304.0f;
}

extern "C" void kernel_launch(void* const* d_in, const int* in_sizes, int n_in,
                              void* d_out, int out_size, void* d_ws, size_t ws_size,
                              hipStream_t stream) {
    const float* x     = (const float*)d_in[0];
    const float* w     = (const float*)d_in[1];
    const float* ecs   = (const float*)d_in[2];
    const float* ema_w = (const float*)d_in[3];
    float* out = (float*)d_out;
    float* ws  = (float*)d_ws;

    float* wsqh   = ws + W_WSQ;
    int*   cnt    = (int*)(ws + W_CNT);
    float* loss_a = ws + W_LOSS;
    float* esum   = ws + W_ESUM;
    int*   rcnt   = (int*)(ws + W_RCNT);
    int*   prefix = (int*)(ws + W_PRE);
    u64*   keys   = (u64*)(ws + W_KEY);
    int*   nsorted= (int*)(ws + W_NSORT);  // overlays keys (dead after combine)
    float* b2s    = ws + W_B2;
    int*   idx_a  = (int*)(ws + W_IDX);    // overlays b2s slice 0 (same-thread RAW)
    int*   rank   = (int*)(ws + W_RANK);   // overlays b2s slice 1 (same-thread RAW)
    int*   rlist  = (int*)(ws + W_RLIST);

    // bf16 hi/lo codebook scratch in the O_Q region (dead after argmin)
    __bf16* wh = (__bf16*)out;
    __bf16* wl = wh + NUM_K * CDIM;

    prep_kernel<<<NUM_K / 4, 256, 0, stream>>>(w, wsqh, wh, wl, cnt, loss_a, rcnt, ecs, esum);
    argmin_mfma<<<dim3(NVEC / 128, 2), 256, 33792, stream>>>(x, wh, wl, wsqh, keys, b2s);
    combine_kernel<<<NVEC / 256, 256, 0, stream>>>(keys, b2s, cnt, idx_a, rank, rcnt, rlist, out);
    rescue_kernel<<<256, 256, 0, stream>>>(x, w, wsqh, idx_a, rank, cnt, rcnt, rlist, out);
    prefix_kernel<<<1, 256, 0, stream>>>(cnt, prefix);
    nsort_kernel<<<NVEC / 256, 256, 0, stream>>>(idx_a, rank, prefix, nsorted);
    qgather_kernel<<<NVEC / 64, 256, 0, stream>>>(x, w, idx_a, out, loss_a);
    dwsum_fin_kernel<<<NUM_K / 4, 256, 0, stream>>>(x, nsorted, cnt, prefix, ecs, ema_w,
                                                    esum, loss_a, out);
}